// Round 5
// baseline (307.796 us; speedup 1.0000x reference)
//
#include <hip/hip_runtime.h>
#include <hip/hip_bf16.h>
#include <math.h>

#define B_ 2
#define S_ 2048
#define H_ 4
#define D_ 64
#define W_ 64
#define ST 4                 // s-positions per block (1 per wave)
#define SROW (H_ * D_)       // 256 elements between consecutive s rows
#define WSTR 104             // Wst col stride: 208B = 13 granules, odd -> conflict-free
#define L2T 2144             // v2t row: 64 zero-pad + 2048 + 32 zero-pad
#define QSC 0.18033688011112042f   // (1/sqrt(64)) * log2(e), folded into q

typedef __attribute__((ext_vector_type(8))) short short8;     // 8 bf16 (MFMA A/B frag)
typedef __attribute__((ext_vector_type(4))) float f32x4;      // MFMA C/D frag
typedef __attribute__((ext_vector_type(2))) unsigned int u32x2;
typedef __attribute__((ext_vector_type(4))) unsigned int u32x4;

__device__ __forceinline__ unsigned pkbf(float lo, float hi) {  // 2xf32 -> packed bf16 (1 inst)
    unsigned r;
    asm("v_cvt_pk_bf16_f32 %0, %1, %2" : "=v"(r) : "v"(lo), "v"(hi));
    return r;
}

__device__ __forceinline__ unsigned short cbf(float f) {
    __hip_bfloat16 h = __float2bfloat16(f);
    unsigned short u;
    __builtin_memcpy(&u, &h, 2);
    return u;
}

// ---- prologue 1: k2 f32 -> bf16 (same layout) ----
__global__ __launch_bounds__(256)
void cvt_k2(const float* __restrict__ in, unsigned short* __restrict__ outp, int n8) {
    int i = blockIdx.x * 256 + threadIdx.x;
    if (i >= n8) return;
    float4 x = ((const float4*)in)[2 * i];
    float4 y = ((const float4*)in)[2 * i + 1];
    u32x4 o = { pkbf(x.x, x.y), pkbf(x.z, x.w), pkbf(y.x, y.y), pkbf(y.z, y.w) };
    *(u32x4*)(outp + 8 * (size_t)i) = o;
}

// ---- prologue 2: v2 -> bf16 transposed [b][h][d][L2T], zero pads both ends ----
__global__ __launch_bounds__(256)
void v2t_kernel(const float* __restrict__ v2, unsigned short* __restrict__ v2t) {
    const int s0 = blockIdx.x * 64;
    const int h = blockIdx.y, b = blockIdx.z;
    const int tid = threadIdx.x;
    __shared__ unsigned short t[64][72];
    const size_t base_bh = (size_t)(b * S_ * H_ + h) * D_;
    const int d = tid & 63;
    for (int i = tid >> 6; i < 64; i += 4)
        t[d][i] = cbf(v2[base_bh + (size_t)(s0 + i) * SROW + d]);
    __syncthreads();
    const size_t obase = ((size_t)(b * H_ + h) * D_) * L2T;
    const short8 z = {0,0,0,0,0,0,0,0};
    for (int idx = tid; idx < 64 * 8; idx += 256) {
        int dd = idx >> 3, c8 = idx & 7;
        *(short8*)(v2t + obase + (size_t)dd * L2T + 64 + s0 + c8 * 8) = *(short8*)&t[dd][c8 * 8];
        if (blockIdx.x == 0)
            *(short8*)(v2t + obase + (size_t)dd * L2T + c8 * 8) = z;           // left pad [0,64)
    }
    if (blockIdx.x == (S_ / 64) - 1) {
        for (int idx = tid; idx < 64 * 4; idx += 256) {
            int dd = idx >> 2, c8 = idx & 3;
            *(short8*)(v2t + obase + (size_t)dd * L2T + 64 + S_ + c8 * 8) = z;  // right pad
        }
    }
}

// ---- main body (EDGE: clamps + amin masking; fast path: mask-free interior) ----
template<bool EDGE>
__device__ __forceinline__ void tsbody(
    const float* __restrict__ q, const float* __restrict__ k1,
    const unsigned short* __restrict__ k2b, const float* __restrict__ v1,
    const unsigned short* __restrict__ v2t, float* __restrict__ out,
    unsigned short (*Wst)[WSTR],
    int s, int base_bh, int v2base, int m16, int g4, int lane)
{
    const int amin = (EDGE && s < W_) ? (W_ - s) : 0;

    // q fragment values, pre-scaled by SCALE*log2e
    float qf[16];
    {
        const float* qp = q + base_bh + s * SROW + g4 * 8;
        #pragma unroll
        for (int kk = 0; kk < 2; ++kk) {
            float4 x = *(const float4*)(qp + kk * 32);
            float4 y = *(const float4*)(qp + kk * 32 + 4);
            qf[kk*8+0]=x.x*QSC; qf[kk*8+1]=x.y*QSC; qf[kk*8+2]=x.z*QSC; qf[kk*8+3]=x.w*QSC;
            qf[kk*8+4]=y.x*QSC; qf[kk*8+5]=y.y*QSC; qf[kk*8+6]=y.z*QSC; qf[kk*8+7]=y.w*QSC;
        }
    }

    // K2 fragments (phase-1 A operand): row c = cs*16+m16, k = d
    short8 b1[5][2];
    #pragma unroll
    for (int cs = 0; cs < 5; ++cs) {
        int j = s - W_ + cs * 16 + m16;
        if (EDGE) j = j < 0 ? 0 : (j > S_ - 1 ? S_ - 1 : j);
        const unsigned short* kp = k2b + base_bh + j * SROW + g4 * 8;
        b1[cs][0] = *(const short8*)kp;
        b1[cs][1] = *(const short8*)(kp + 32);
    }

    // V2 fragments (phase-2 B operand) straight from padded transposed global
    short8 b2[4][3];
    #pragma unroll
    for (int dn = 0; dn < 4; ++dn) {
        const unsigned short* vp = v2t + v2base + (dn * 16 + m16) * L2T + s;
        #pragma unroll
        for (int kk = 0; kk < 3; ++kk)
            b2[dn][kk] = *(const short8*)(vp + kk * 32 + g4 * 8);   // pads absorb OOB
    }

    // zero K-pad cols [80,96) of this wave's Wst (persists across strips)
    *(u32x2*)&Wst[m16][80 + g4 * 4] = (u32x2){0u, 0u};

    float dsum = 0.f;
    float pnum[4] = {0.f, 0.f, 0.f, 0.f};

    const float* k1p0 = k1 + base_bh + (s - W_ + m16) * SROW + g4 * 8;
    const float* v1p0 = v1 + base_bh + (s - W_ + g4 * 4) * SROW + m16;

    #pragma unroll
    for (int strip = 0; strip < 5; ++strip) {
        // P^T fragment (phase-1 B operand): col a = strip*16+m16, k = d
        short8 a1[2];
        {
            const float* kp;
            if (EDGE) {
                int j = s - W_ + strip * 16 + m16;
                j = j < 0 ? 0 : (j > S_ - 1 ? S_ - 1 : j);
                kp = k1 + base_bh + j * SROW + g4 * 8;
            } else {
                kp = k1p0 + strip * 16 * SROW;
            }
            #pragma unroll
            for (int kk = 0; kk < 2; ++kk) {
                float4 x = *(const float4*)(kp + kk * 32);
                float4 y = *(const float4*)(kp + kk * 32 + 4);
                u32x4 o = { pkbf(x.x * qf[kk*8+0], x.y * qf[kk*8+1]),
                            pkbf(x.z * qf[kk*8+2], x.w * qf[kk*8+3]),
                            pkbf(y.x * qf[kk*8+4], y.y * qf[kk*8+5]),
                            pkbf(y.z * qf[kk*8+6], y.w * qf[kk*8+7]) };
                a1[kk] = *(short8*)&o;
            }
        }

        // S^T tiles: D[m=c][n=a] = sum_d K2[c][d] * P[a][d]
        f32x4 acc1[5];
        #pragma unroll
        for (int cs = 0; cs < 5; ++cs) {
            acc1[cs] = (f32x4){0.f, 0.f, 0.f, 0.f};
            #pragma unroll
            for (int kk = 0; kk < 2; ++kk)
                acc1[cs] = __builtin_amdgcn_mfma_f32_16x16x32_bf16(b1[cs][kk], a1[kk], acc1[cs], 0, 0, 0);
        }

        // exp -> Wst[a_local=m16][c] as packed b64 writes (4 consecutive c per lane)
        const int abs_a = strip * 16 + m16;
        const bool aok = EDGE ? (abs_a >= amin && abs_a <= W_) : (abs_a <= W_);
        #pragma unroll
        for (int cs = 0; cs < 5; ++cs) {
            float e[4];
            #pragma unroll
            for (int r = 0; r < 4; ++r) {
                const int c = cs * 16 + g4 * 4 + r;
                const bool ok = aok && (c <= W_) && (!EDGE || c >= amin);
                const float wv = ok ? __builtin_amdgcn_exp2f(acc1[cs][r]) : 0.f;
                dsum += wv;
                e[r] = wv;
            }
            *(u32x2*)&Wst[m16][cs * 16 + g4 * 4] = (u32x2){ pkbf(e[0], e[1]), pkbf(e[2], e[3]) };
        }

        // phase 2: U[a][d] = sum_c W[a][c] * v2[c][d], K=96
        short8 a2[3];
        #pragma unroll
        for (int kk = 0; kk < 3; ++kk)
            a2[kk] = *(const short8*)&Wst[m16][kk * 32 + g4 * 8];

        #pragma unroll
        for (int dn = 0; dn < 4; ++dn) {
            f32x4 acc2 = (f32x4){0.f, 0.f, 0.f, 0.f};
            #pragma unroll
            for (int kk = 0; kk < 3; ++kk)
                acc2 = __builtin_amdgcn_mfma_f32_16x16x32_bf16(a2[kk], b2[dn][kk], acc2, 0, 0, 0);
            #pragma unroll
            for (int r = 0; r < 4; ++r) {
                float v1v;
                if (EDGE) {
                    int j = s - W_ + strip * 16 + g4 * 4 + r;
                    j = j < 0 ? 0 : (j > S_ - 1 ? S_ - 1 : j);
                    v1v = v1[base_bh + j * SROW + dn * 16 + m16];
                } else {
                    v1v = v1p0[strip * 16 * SROW + r * SROW + dn * 16];  // imm offsets
                }
                pnum[dn] += acc2[r] * v1v;   // invalid rows: acc2 == 0
            }
        }
    }

    #pragma unroll
    for (int off = 32; off >= 1; off >>= 1) dsum += __shfl_xor(dsum, off, 64);
    #pragma unroll
    for (int dn = 0; dn < 4; ++dn) {
        pnum[dn] += __shfl_xor(pnum[dn], 16, 64);
        pnum[dn] += __shfl_xor(pnum[dn], 32, 64);
    }
    if (lane < 16) {
        const float inv = 1.f / (dsum + 1e-8f);
        #pragma unroll
        for (int dn = 0; dn < 4; ++dn)
            out[base_bh + s * SROW + dn * 16 + lane] = pnum[dn] * inv;
    }
}

__global__ __launch_bounds__(256, 3)
void tsattn_mfma(const float* __restrict__ q, const float* __restrict__ k1,
                 const unsigned short* __restrict__ k2b, const float* __restrict__ v1,
                 const unsigned short* __restrict__ v2t, float* __restrict__ out)
{
    __shared__ unsigned short Wst[ST][16][WSTR];   // 13,312 B total; only LDS in kernel
    const int s0 = blockIdx.x * ST;
    const int h = blockIdx.y, b = blockIdx.z;
    const int tid = threadIdx.x, lane = tid & 63, w = tid >> 6;
    const int m16 = lane & 15, g4 = lane >> 4;
    const int s = s0 + w;
    const int base_bh = b * S_ * SROW + h * D_;
    const int v2base = ((b * H_ + h) * D_) * L2T;
    const bool edge = (s0 < W_) || (s0 + 18 > S_ - 1);
    if (edge)
        tsbody<true >(q, k1, k2b, v1, v2t, out, Wst[w], s, base_bh, v2base, m16, g4, lane);
    else
        tsbody<false>(q, k1, k2b, v1, v2t, out, Wst[w], s, base_bh, v2base, m16, g4, lane);
}

extern "C" void kernel_launch(void* const* d_in, const int* in_sizes, int n_in,
                              void* d_out, int out_size, void* d_ws, size_t ws_size,
                              hipStream_t stream) {
    const float* q  = (const float*)d_in[0];
    const float* k1 = (const float*)d_in[1];
    const float* k2 = (const float*)d_in[2];
    const float* v1 = (const float*)d_in[3];
    const float* v2 = (const float*)d_in[4];
    float* out = (float*)d_out;

    const size_t NE = (size_t)B_ * S_ * H_ * D_;   // 1,048,576
    unsigned short* k2b = (unsigned short*)d_ws;
    unsigned short* v2t = k2b + NE;                // B*H*D*L2T = 1,097,728 ushorts

    const int n8 = (int)(NE / 8);
    cvt_k2<<<(n8 + 255) / 256, 256, 0, stream>>>(k2, k2b, n8);
    v2t_kernel<<<dim3(S_ / 64, H_, B_), 256, 0, stream>>>(v2, v2t);

    tsattn_mfma<<<dim3(S_ / ST, H_, B_), 256, 0, stream>>>(q, k1, k2b, v1, v2t, out);
}